// Round 2
// baseline (842.634 us; speedup 1.0000x reference)
//
#include <hip/hip_runtime.h>

// Problem: B=4, H=32, S=4096, T=1, D=128, fp32.
// out = concat(k_new, v_new) flat; k_new = [B,H,S+1,D] = k_cache rows then k_val row per (b,h).
//
// All in float4 units:
//   per-(b,h) cache chunk : S*D/4     = 131072  (= 2^17)
//   per-(b,h) out chunk   : (S+1)*D/4 = 131104
//   cache half size       : 128*131072 = 16777216 (= 2^24)
//   out half size         : 128*131104 = 16781312
//   bulk (both caches)    : 2*2^24 = 2^25 float4
//   tail (k_val+v_val)    : 2*128*32 = 8192 float4
//
// Structure: 2048 blocks x 256 threads = 2^19 threads. Each outer iteration a
// thread handles 4 float4 at indices tid + j*2^19 (j=0..3): every load/store
// instruction is unit-stride across the wave (perfect coalescing), and each
// thread keeps 4 loads in flight (MLP) instead of 1-load-wait-store.
// 16 iterations cover the 2^25 bulk exactly. Non-temporal: streamed once,
// no reuse -> don't pollute L2/LLC.

typedef float f4 __attribute__((ext_vector_type(4)));

#define CHUNK4    131072L
#define OUTCHUNK4 131104L
#define HALF4     16777216L
#define OUTHALF4  16781312L
#define NTHREADS  524288L     // 2048 * 256 = 2^19
#define TAIL4     8192L

__global__ __launch_bounds__(256) void kv_append_kernel(
    const f4* __restrict__ kc, const f4* __restrict__ vc,
    const f4* __restrict__ kv, const f4* __restrict__ vv,
    f4* __restrict__ out)
{
    const long tid = (long)blockIdx.x * 256 + threadIdx.x;

    long base = tid;
#pragma unroll 1
    for (int it = 0; it < 16; ++it) {
        f4 v[4];
        // Issue all 4 loads first (independent -> 4 outstanding vmem ops).
#pragma unroll
        for (int j = 0; j < 4; ++j) {
            long idx  = base + (long)j * NTHREADS;   // < 2^25 by construction
            long half = idx >> 24;                   // 0 = k, 1 = v
            long rem  = idx & (HALF4 - 1);
            const f4* __restrict__ src = half ? vc : kc;
            v[j] = __builtin_nontemporal_load(&src[rem]);
        }
#pragma unroll
        for (int j = 0; j < 4; ++j) {
            long idx  = base + (long)j * NTHREADS;
            long half = idx >> 24;
            long rem  = idx & (HALF4 - 1);
            long dst  = half * OUTHALF4 + (rem >> 17) * OUTCHUNK4 + (rem & (CHUNK4 - 1));
            __builtin_nontemporal_store(v[j], &out[dst]);
        }
        base += 4 * NTHREADS;
    }

    // Tail: the appended T=1 row per (b,h). 8192 float4, one per thread.
    if (tid < TAIL4) {
        long half = tid >> 12;          // 0 = k_val, 1 = v_val
        long rem  = tid & 4095L;        // index into val half (BH * D/4)
        const f4* __restrict__ src = half ? vv : kv;
        f4 val = __builtin_nontemporal_load(&src[rem]);
        long dst = half * OUTHALF4 + (rem >> 5) * OUTCHUNK4 + CHUNK4 + (rem & 31L);
        __builtin_nontemporal_store(val, &out[dst]);
    }
}

extern "C" void kernel_launch(void* const* d_in, const int* in_sizes, int n_in,
                              void* d_out, int out_size, void* d_ws, size_t ws_size,
                              hipStream_t stream) {
    const f4* kc = (const f4*)d_in[0];
    const f4* vc = (const f4*)d_in[1];
    const f4* kv = (const f4*)d_in[2];
    const f4* vv = (const f4*)d_in[3];
    f4* out = (f4*)d_out;

    kv_append_kernel<<<dim3(2048), dim3(256), 0, stream>>>(kc, vc, kv, vv, out);
}